// Round 11
// baseline (1994.905 us; speedup 1.0000x reference)
//
#include <hip/hip_runtime.h>

#define NCB 9
#define KCB 1024
#define CD 8
#define DD 64
#define TT 32768
#define BB 4

#define ZQ_SZ (BB*DD*TT)              // 8388608
#define CODES_OFF ZQ_SZ
#define CODES_SZ (BB*NCB*TT)          // 1179648
#define LAT_OFF (CODES_OFF + CODES_SZ)
#define LAT_SZ (BB*NCB*CD*TT)         // 9437184
#define LOSS_OFF (LAT_OFF + LAT_SZ)   // 19005440

// ---- d_ws byte layout ----
#define OFF_CBN32    0          // 73728 f32  = 294912
#define OFF_CBN64    294912     // 73728 f64  = 589824
#define OFF_SCBK64   884736     // 9216 f64   = 73728
#define OFF_WIN64    958464     // 4608 f64   = 36864
#define OFF_WOUT64   995328     // 4608 f64   = 36864
#define OFF_BIN64    1032192    // 72 f64     = 576
#define OFF_BOUT64   1032768    // 576 f64    = 4608
#define OFF_LOSSPART 1037376    // 256 f64    = 2048

__global__ void prep_cb(const float* __restrict__ cb,
                        float* __restrict__ cbn32,
                        double* __restrict__ cbn64, double* __restrict__ scbk64) {
  int r = blockIdx.x * blockDim.x + threadIdx.x;
  if (r >= NCB * KCB) return;
  double v[CD], s = 0.0;
#pragma unroll
  for (int c = 0; c < CD; c++) { v[c] = (double)cb[r*CD + c]; s += v[c]*v[c]; }
  double den = fmax(sqrt(s), 1e-12);
  double s2 = 0.0;
#pragma unroll
  for (int c = 0; c < CD; c++) {
    double o = v[c] / den;
    cbn64[r*CD + c] = o;
    cbn32[r*CD + c] = (float)o;
    s2 += o*o;
  }
  scbk64[r] = s2;
}

__global__ void prep_w(const float* __restrict__ W_in, const float* __restrict__ b_in,
                       const float* __restrict__ W_out, const float* __restrict__ b_out,
                       double* __restrict__ Win64, double* __restrict__ bin64,
                       double* __restrict__ Wout64, double* __restrict__ bout64) {
  int i = blockIdx.x * blockDim.x + threadIdx.x;
  if (i < NCB*CD*DD) Win64[i]  = (double)W_in[i];
  if (i < NCB*CD*DD) Wout64[i] = (double)W_out[i];
  if (i < NCB*CD)    bin64[i]  = (double)b_in[i];
  if (i < NCB*DD)    bout64[i] = (double)b_out[i];
}

#define DOT8(e, v0, v1) \
  fmaf((e)[7],(v1).w, fmaf((e)[6],(v1).z, fmaf((e)[5],(v1).y, fmaf((e)[4],(v1).x, \
  fmaf((e)[3],(v0).w, fmaf((e)[2],(v0).z, fmaf((e)[1],(v0).y, (e)[0]*(v0).x)))))))

#define SEL(dot, best, best2, bidx, kval) { \
  float ob_ = (best); \
  (best2) = __builtin_amdgcn_fmed3f(ob_, (best2), (dot)); \
  (best)  = fmaxf(ob_, (dot)); \
  (bidx)  = ((dot) > ob_) ? (kval) : (bidx); }

// 2 positions per thread: each LDS row-read (2x b128) is dotted against TWO
// encs, halving LDS return-bytes per dot (R10 diagnosis: 13.4 cyc/b128
// broadcast throughput is the wall, not latency — batch-4 gave only 5%).
// 65536 threads, grid 256 = 1 block/CU = 4 waves/CU. __launch_bounds__(256,1)
// gives the 512-unified-register budget for two f64 residual chains (r parked
// in AGPRs; R9 lesson: header VGPR=128 can still spill if unified overflows).
__global__ __launch_bounds__(256, 1) void rvq_kernel(
    const float* __restrict__ x,
    const float* __restrict__ cb,
    const double* __restrict__ Win64,
    const double* __restrict__ bin64,
    const double* __restrict__ Wout64,
    const double* __restrict__ bout64,
    const float* __restrict__ cbn32,
    const double* __restrict__ cbn64,
    const double* __restrict__ scbk64,
    float* __restrict__ out,
    double* __restrict__ loss_part) {
  __shared__ __align__(16) float cb_lds[KCB * CD];   // 32 KB
  __shared__ double wsum[4];

  const int tid = blockIdx.x * 256 + threadIdx.x;   // [0, 65536)
  const int b0 = tid >> 15;            // 0 or 1
  const int t  = tid & (TT - 1);
  const int b1 = b0 + 2;               // position 2: tid + 65536

  double r0[DD], r1[DD];
#pragma unroll
  for (int d = 0; d < DD; d++) {
    r0[d] = (double)x[(b0*DD + d)*TT + t];
    r1[d] = (double)x[(b1*DD + d)*TT + t];
  }

  double lacc = 0.0;

#pragma unroll 1
  for (int i = 0; i < NCB; i++) {
    // ---- stage codebook i into LDS
    __syncthreads();
    {
      const float4* __restrict__ src = (const float4*)(cbn32 + i*KCB*CD);
      float4* __restrict__ dst = (float4*)cb_lds;
#pragma unroll
      for (int c0 = 0; c0 < 8; c0++)
        dst[c0*256 + threadIdx.x] = src[c0*256 + threadIdx.x];
    }
    __syncthreads();

    // ---- in_proj (f64), weights shared across both positions
    double ze0[CD], ze1[CD];
#pragma unroll
    for (int c = 0; c < CD; c++) {
      const double* __restrict__ W = Win64 + (i*CD + c)*DD;
      double a0 = 0.0, a1 = 0.0;
#pragma unroll
      for (int d = 0; d < DD; d++) {
        double w = W[d];
        a0 = fma(w, r0[d], a0);
        a1 = fma(w, r1[d], a1);
      }
      double bi = bin64[i*CD + c];
      ze0[c] = a0 + bi;
      ze1[c] = a1 + bi;
    }

    // ---- normalize both
    double s00 = 0.0, s01 = 0.0;
#pragma unroll
    for (int c = 0; c < CD; c++) { s00 = fma(ze0[c], ze0[c], s00); s01 = fma(ze1[c], ze1[c], s01); }
    double inv0 = 1.0 / fmax(sqrt(s00), 1e-12);
    double inv1 = 1.0 / fmax(sqrt(s01), 1e-12);
    float encf0[CD], encf1[CD];
#pragma unroll
    for (int c = 0; c < CD; c++) {
      encf0[c] = (float)(ze0[c] * inv0);
      encf1[c] = (float)(ze1[c] * inv1);
    }

    // ---- latents early (frees ze from the scan's hot set)
#pragma unroll
    for (int c = 0; c < CD; c++) {
      out[LAT_OFF + (b0*NCB*CD + i*CD + c)*TT + t] = (float)ze0[c];
      out[LAT_OFF + (b1*NCB*CD + i*CD + c)*TT + t] = (float)ze1[c];
    }

    // ---- f32 max-dot scan: each row read once, dotted against both encs
    const float4* __restrict__ lb = (const float4*)cb_lds;
    float best0 = -3.402823466e38f, best20 = -3.402823466e38f;
    float best1 = -3.402823466e38f, best21 = -3.402823466e38f;
    int bidx0 = 0, bidx1 = 0;
#pragma unroll 2
    for (int kk = 0; kk < KCB; kk += 2) {
      float4 ra0 = lb[2*kk + 0], ra1 = lb[2*kk + 1];
      float4 rb0 = lb[2*kk + 2], rb1 = lb[2*kk + 3];
      float dA0 = DOT8(encf0, ra0, ra1);
      float dA1 = DOT8(encf1, ra0, ra1);
      float dB0 = DOT8(encf0, rb0, rb1);
      float dB1 = DOT8(encf1, rb0, rb1);
      SEL(dA0, best0, best20, bidx0, kk);
      SEL(dA1, best1, best21, bidx1, kk);
      SEL(dB0, best0, best20, bidx0, kk + 1);
      SEL(dB1, best1, best21, bidx1, kk + 1);
    }

    // ---- near-tie: authoritative f64 rescans (rare, exec-masked)
    if (best0 - best20 < 1.2e-5f) {
      const double* __restrict__ cb64 = cbn64 + i*KCB*CD;
      const double* __restrict__ s64  = scbk64 + i*KCB;
      double enc64[CD], s_enc = 0.0;
#pragma unroll
      for (int c = 0; c < CD; c++) { enc64[c] = ze0[c] * inv0; s_enc = fma(enc64[c], enc64[c], s_enc); }
      double bd = 1e300; int bk = 0;
#pragma unroll 4
      for (int k = 0; k < KCB; k++) {
        double dot = 0.0;
#pragma unroll
        for (int c = 0; c < CD; c++) dot = fma(enc64[c], cb64[k*CD + c], dot);
        double dist = fma(-2.0, dot, s_enc) + s64[k];
        if (dist < bd) { bd = dist; bk = k; }
      }
      bidx0 = bk;
    }
    if (best1 - best21 < 1.2e-5f) {
      const double* __restrict__ cb64 = cbn64 + i*KCB*CD;
      const double* __restrict__ s64  = scbk64 + i*KCB;
      double enc64[CD], s_enc = 0.0;
#pragma unroll
      for (int c = 0; c < CD; c++) { enc64[c] = ze1[c] * inv1; s_enc = fma(enc64[c], enc64[c], s_enc); }
      double bd = 1e300; int bk = 0;
#pragma unroll 4
      for (int k = 0; k < KCB; k++) {
        double dot = 0.0;
#pragma unroll
        for (int c = 0; c < CD; c++) dot = fma(enc64[c], cb64[k*CD + c], dot);
        double dist = fma(-2.0, dot, s_enc) + s64[k];
        if (dist < bd) { bd = dist; bk = k; }
      }
      bidx1 = bk;
    }

    // ---- gather raw codebook rows
    const float4* __restrict__ q0p = (const float4*)(cb + (i*KCB + bidx0)*CD);
    const float4* __restrict__ q1p = (const float4*)(cb + (i*KCB + bidx1)*CD);
    float4 q00 = q0p[0], q01 = q0p[1];
    float4 q10 = q1p[0], q11 = q1p[1];
    double zq0[CD] = {(double)q00.x, (double)q00.y, (double)q00.z, (double)q00.w,
                      (double)q01.x, (double)q01.y, (double)q01.z, (double)q01.w};
    double zq1[CD] = {(double)q10.x, (double)q10.y, (double)q10.z, (double)q10.w,
                      (double)q11.x, (double)q11.y, (double)q11.z, (double)q11.w};

    // ---- losses
#pragma unroll
    for (int c = 0; c < CD; c++) {
      double d0 = ze0[c] - zq0[c];
      double d1 = ze1[c] - zq1[c];
      lacc = fma(d0, d0, lacc);
      lacc = fma(d1, d1, lacc);
    }

    // ---- out_proj (f64), weights shared + residual updates
#pragma unroll
    for (int d = 0; d < DD; d++) {
      const double* __restrict__ Wo = Wout64 + (i*DD + d)*CD;
      double bo = bout64[i*DD + d];
      double a0 = bo, a1 = bo;
#pragma unroll
      for (int c = 0; c < CD; c++) {
        double w = Wo[c];
        a0 = fma(w, zq0[c], a0);
        a1 = fma(w, zq1[c], a1);
      }
      r0[d] -= a0;
      r1[d] -= a1;
    }

    // ---- codes
    out[CODES_OFF + (b0*NCB + i)*TT + t] = (float)bidx0;
    out[CODES_OFF + (b1*NCB + i)*TT + t] = (float)bidx1;
  }

  // ---- z_q = x - residual_final
#pragma unroll
  for (int d = 0; d < DD; d++) {
    out[(b0*DD + d)*TT + t] = (float)((double)x[(b0*DD + d)*TT + t] - r0[d]);
    out[(b1*DD + d)*TT + t] = (float)((double)x[(b1*DD + d)*TT + t] - r1[d]);
  }

  // ---- deterministic loss reduction
#pragma unroll
  for (int off = 32; off > 0; off >>= 1)
    lacc += __shfl_down(lacc, off, 64);
  int wv = threadIdx.x >> 6;
  if ((threadIdx.x & 63) == 0) wsum[wv] = lacc;
  __syncthreads();
  if (threadIdx.x == 0)
    loss_part[blockIdx.x] = wsum[0] + wsum[1] + wsum[2] + wsum[3];
}

__global__ void loss_final(const double* __restrict__ loss_part,
                           float* __restrict__ out) {
  __shared__ double sh[256];
  sh[threadIdx.x] = loss_part[threadIdx.x];   // 256 blocks -> 256 partials
  __syncthreads();
  for (int off = 128; off > 0; off >>= 1) {
    if (threadIdx.x < off) sh[threadIdx.x] += sh[threadIdx.x + off];
    __syncthreads();
  }
  if (threadIdx.x == 0) {
    double v = sh[0] / ((double)NCB * (double)BB * (double)CD * (double)TT);
    out[LOSS_OFF]     = (float)v;   // commit
    out[LOSS_OFF + 1] = (float)v;   // cb_loss (equal in forward value)
  }
}

extern "C" void kernel_launch(void* const* d_in, const int* in_sizes, int n_in,
                              void* d_out, int out_size, void* d_ws, size_t ws_size,
                              hipStream_t stream) {
  const float* x     = (const float*)d_in[0];
  const float* W_in  = (const float*)d_in[1];
  const float* b_in  = (const float*)d_in[2];
  const float* cb    = (const float*)d_in[3];
  const float* W_out = (const float*)d_in[4];
  const float* b_out = (const float*)d_in[5];
  float* out = (float*)d_out;

  char* ws = (char*)d_ws;
  float*  cbn32  = (float*)(ws + OFF_CBN32);
  double* cbn64  = (double*)(ws + OFF_CBN64);
  double* scbk64 = (double*)(ws + OFF_SCBK64);
  double* Win64  = (double*)(ws + OFF_WIN64);
  double* Wout64 = (double*)(ws + OFF_WOUT64);
  double* bin64  = (double*)(ws + OFF_BIN64);
  double* bout64 = (double*)(ws + OFF_BOUT64);
  double* loss_part = (double*)(ws + OFF_LOSSPART);

  prep_cb<<<(NCB*KCB + 255)/256, 256, 0, stream>>>(cb, cbn32, cbn64, scbk64);
  prep_w<<<(NCB*CD*DD + 255)/256, 256, 0, stream>>>(W_in, b_in, W_out, b_out,
                                                    Win64, bin64, Wout64, bout64);
  rvq_kernel<<<256, 256, 0, stream>>>(x, cb, Win64, bin64, Wout64, bout64,
                                      cbn32, cbn64, scbk64, out, loss_part);
  loss_final<<<1, 256, 0, stream>>>(loss_part, out);
}

// Round 12
// 542.722 us; speedup vs baseline: 3.6757x; 3.6757x over previous
//
#include <hip/hip_runtime.h>

#define NCB 9
#define KCB 1024
#define CD 8
#define DD 64
#define TT 32768
#define BB 4

#define ZQ_SZ (BB*DD*TT)              // 8388608
#define CODES_OFF ZQ_SZ
#define CODES_SZ (BB*NCB*TT)          // 1179648
#define LAT_OFF (CODES_OFF + CODES_SZ)
#define LAT_SZ (BB*NCB*CD*TT)         // 9437184
#define LOSS_OFF (LAT_OFF + LAT_SZ)   // 19005440

// ---- d_ws byte layout (cbsplit reuses the old cbn32 slot, same size) ----
#define OFF_CBSPLIT  0          // 9216 codes * 32B (bf16 hi[8]|lo[8]) = 294912
#define OFF_CBN64    294912     // 73728 f64  = 589824
#define OFF_SCBK64   884736     // 9216 f64   = 73728
#define OFF_WIN64    958464     // 4608 f64   = 36864
#define OFF_WOUT64   995328     // 4608 f64   = 36864
#define OFF_BIN64    1032192    // 72 f64     = 576
#define OFF_BOUT64   1032768    // 576 f64    = 4608
#define OFF_LOSSPART 1037376    // 512 f64    = 4096

#define MARGIN 1e-4f

typedef __attribute__((ext_vector_type(8))) short short8;
typedef __attribute__((ext_vector_type(4))) float f32x4;

__device__ __forceinline__ unsigned bf16rtn(float x) {
  unsigned u = __float_as_uint(x);
  return (u + 0x7fffu + ((u >> 16) & 1u)) >> 16;   // RTN bf16 (no NaN inputs here)
}

__global__ void prep_cb(const float* __restrict__ cb,
                        unsigned* __restrict__ cbsplit,
                        double* __restrict__ cbn64, double* __restrict__ scbk64) {
  int r = blockIdx.x * blockDim.x + threadIdx.x;
  if (r >= NCB * KCB) return;
  double v[CD], s = 0.0;
#pragma unroll
  for (int c = 0; c < CD; c++) { v[c] = (double)cb[r*CD + c]; s += v[c]*v[c]; }
  double den = fmax(sqrt(s), 1e-12);
  double s2 = 0.0;
  float of[CD];
#pragma unroll
  for (int c = 0; c < CD; c++) {
    double o = v[c] / den;
    cbn64[r*CD + c] = o;
    of[c] = (float)o;
    s2 += o*o;
  }
  scbk64[r] = s2;
  unsigned hp[4], lp[4];
#pragma unroll
  for (int c2 = 0; c2 < 4; c2++) {
    float f0 = of[2*c2], f1 = of[2*c2+1];
    unsigned h0 = bf16rtn(f0), h1 = bf16rtn(f1);
    float g0 = f0 - __uint_as_float(h0 << 16);
    float g1 = f1 - __uint_as_float(h1 << 16);
    unsigned l0 = bf16rtn(g0), l1 = bf16rtn(g1);
    hp[c2] = h0 | (h1 << 16);
    lp[c2] = l0 | (l1 << 16);
  }
  int4* dst = (int4*)(cbsplit + (size_t)r*8);
  dst[0] = make_int4((int)hp[0], (int)hp[1], (int)hp[2], (int)hp[3]);
  dst[1] = make_int4((int)lp[0], (int)lp[1], (int)lp[2], (int)lp[3]);
}

__global__ void prep_w(const float* __restrict__ W_in, const float* __restrict__ b_in,
                       const float* __restrict__ W_out, const float* __restrict__ b_out,
                       double* __restrict__ Win64, double* __restrict__ bin64,
                       double* __restrict__ Wout64, double* __restrict__ bout64) {
  int i = blockIdx.x * blockDim.x + threadIdx.x;
  if (i < NCB*CD*DD) Win64[i]  = (double)W_in[i];
  if (i < NCB*CD*DD) Wout64[i] = (double)W_out[i];
  if (i < NCB*CD)    bin64[i]  = (double)b_in[i];
  if (i < NCB*DD)    bout64[i] = (double)b_out[i];
}

// top-2 merge of two (best,best2,idx) triples over DISJOINT candidate sets;
// tie -> smaller index (matches f64 first-index argmin after rescan gate).
#define MERGE(bA,b2A,iA, bB,b2B,iB) { \
  float nb2_ = fmaxf(fminf((bA),(bB)), fmaxf((b2A),(b2B))); \
  bool tk_ = ((bB) > (bA)) || ((bB) == (bA) && (iB) < (iA)); \
  (bA) = fmaxf((bA),(bB)); (b2A) = nb2_; (iA) = tk_ ? (iB) : (iA); }

__global__ __launch_bounds__(256, 2) void rvq_kernel(
    const float* __restrict__ x,
    const float* __restrict__ cb,
    const double* __restrict__ Win64,
    const double* __restrict__ bin64,
    const double* __restrict__ Wout64,
    const double* __restrict__ bout64,
    const unsigned* __restrict__ cbsplit,
    const double* __restrict__ cbn64,
    const double* __restrict__ scbk64,
    float* __restrict__ out,
    double* __restrict__ loss_part) {
  // 32 KB staged split-codebook + 4 waves x 2 KB B-exchange
  __shared__ __align__(16) char ldsbuf[32768 + 8192];
  __shared__ double wsum[4];

  const int lane = threadIdx.x & 63;
  const int wv   = threadIdx.x >> 6;
  const int tid  = blockIdx.x * 256 + threadIdx.x;
  const int b = tid >> 15;            // TT = 2^15
  const int t = tid & (TT - 1);
  const int lanebase = (lane >> 4) * 4;          // C-layout row base
  char* bex = ldsbuf + 32768 + wv * 2048;

  double r[DD];
#pragma unroll
  for (int d = 0; d < DD; d++) r[d] = (double)x[(b*DD + d)*TT + t];

  double lacc = 0.0;

#pragma unroll 1
  for (int i = 0; i < NCB; i++) {
    // ---- stage split codebook i into LDS
    __syncthreads();
    {
      const float4* __restrict__ src = (const float4*)(cbsplit + (size_t)i*KCB*8);
      float4* __restrict__ dst = (float4*)ldsbuf;
#pragma unroll
      for (int c0 = 0; c0 < 8; c0++)
        dst[c0*256 + threadIdx.x] = src[c0*256 + threadIdx.x];
    }
    __syncthreads();

    // ---- in_proj (f64)
    double ze[CD];
#pragma unroll
    for (int c = 0; c < CD; c++) ze[c] = bin64[i*CD + c];
#pragma unroll
    for (int c = 0; c < CD; c++) {
#pragma unroll
      for (int d = 0; d < DD; d++)
        ze[c] = fma(Win64[(i*CD + c)*DD + d], r[d], ze[c]);
    }

    // ---- normalize; f32 enc
    double s0 = 0.0;
#pragma unroll
    for (int c = 0; c < CD; c++) s0 = fma(ze[c], ze[c], s0);
    double inv = 1.0 / fmax(sqrt(s0), 1e-12);
    float encf[CD];
#pragma unroll
    for (int c = 0; c < CD; c++) encf[c] = (float)(ze[c] * inv);

    // ---- latents
#pragma unroll
    for (int c = 0; c < CD; c++)
      out[LAT_OFF + (b*NCB*CD + i*CD + c)*TT + t] = (float)ze[c];

    // ---- pack enc hi/lo bf16, exchange through per-wave LDS (B-fragment transpose)
    {
      unsigned hp[4], lp[4];
#pragma unroll
      for (int c2 = 0; c2 < 4; c2++) {
        float f0 = encf[2*c2], f1 = encf[2*c2+1];
        unsigned h0 = bf16rtn(f0), h1 = bf16rtn(f1);
        float g0 = f0 - __uint_as_float(h0 << 16);
        float g1 = f1 - __uint_as_float(h1 << 16);
        unsigned l0 = bf16rtn(g0), l1 = bf16rtn(g1);
        hp[c2] = h0 | (h1 << 16);
        lp[c2] = l0 | (l1 << 16);
      }
      *(int4*)(bex + lane*32)      = make_int4((int)hp[0],(int)hp[1],(int)hp[2],(int)hp[3]);
      *(int4*)(bex + lane*32 + 16) = make_int4((int)lp[0],(int)lp[1],(int)lp[2],(int)lp[3]);
    }

    int bidxF = 0;
    bool trigF = false;

    // A-fragment base: row=lane&15, k-group=(lane>>4) -> [chi,chi,clo,clo]
    const char* abase = ldsbuf + (lane & 15) * 32 + (((lane >> 4) >> 1) << 4);

#pragma unroll 1
    for (int pt = 0; pt < 4; pt++) {
      // B-fragment: col=lane&15 -> position pt*16+(lane&15); k-group -> [hi,lo,hi,lo]
      int4 bi4 = *(const int4*)(bex + (pt*16 + (lane & 15))*32 + ((lane >> 4) & 1)*16);
      short8 bf8 = __builtin_bit_cast(short8, bi4);

      float bq0 = -3.4e38f, bq1 = -3.4e38f, bq2 = -3.4e38f, bq3 = -3.4e38f;
      float q20 = -3.4e38f, q21 = -3.4e38f, q22 = -3.4e38f, q23 = -3.4e38f;
      int iq0 = 0, iq1 = 0, iq2 = 0, iq3 = 0;
      const f32x4 zero = {0.f, 0.f, 0.f, 0.f};

#pragma unroll 4
      for (int ct = 0; ct < 64; ct++) {
        int4 ai4 = *(const int4*)(abase + ct*512);
        short8 af8 = __builtin_bit_cast(short8, ai4);
        f32x4 Cv = __builtin_amdgcn_mfma_f32_16x16x32_bf16(af8, bf8, zero, 0, 0, 0);
        int kb = ct*16 + lanebase;
        float d0 = Cv[0], d1 = Cv[1], d2 = Cv[2], d3 = Cv[3];
        float ob;
        ob = bq0; q20 = __builtin_amdgcn_fmed3f(ob, q20, d0);
        bq0 = fmaxf(ob, d0); iq0 = (d0 > ob) ? (kb + 0) : iq0;
        ob = bq1; q21 = __builtin_amdgcn_fmed3f(ob, q21, d1);
        bq1 = fmaxf(ob, d1); iq1 = (d1 > ob) ? (kb + 1) : iq1;
        ob = bq2; q22 = __builtin_amdgcn_fmed3f(ob, q22, d2);
        bq2 = fmaxf(ob, d2); iq2 = (d2 > ob) ? (kb + 2) : iq2;
        ob = bq3; q23 = __builtin_amdgcn_fmed3f(ob, q23, d3);
        bq3 = fmaxf(ob, d3); iq3 = (d3 > ob) ? (kb + 3) : iq3;
      }

      // in-lane q merges, then cross-lane (xor16, xor32)
      MERGE(bq0, q20, iq0, bq1, q21, iq1);
      MERGE(bq2, q22, iq2, bq3, q23, iq3);
      MERGE(bq0, q20, iq0, bq2, q22, iq2);
#pragma unroll
      for (int m = 16; m <= 32; m <<= 1) {
        float obm  = __shfl_xor(bq0, m, 64);
        float ob2m = __shfl_xor(q20, m, 64);
        int   oim  = __shfl_xor(iq0, m, 64);
        MERGE(bq0, q20, iq0, obm, ob2m, oim);
      }

      bool own = ((lane >> 4) == pt);
      bidxF = own ? iq0 : bidxF;
      trigF = own ? (bq0 - q20 < MARGIN) : trigF;
    }

    // ---- near-tie: cooperative f64 rescan (wave-parallel, ~1K cyc/trigger)
    {
      unsigned long long bal = __ballot(trigF);
      while (bal) {
        int j = __builtin_ctzll(bal);
        bal &= bal - 1;
        double invb = __shfl(inv, j, 64);
        double encb[CD], se = 0.0;
#pragma unroll
        for (int c = 0; c < CD; c++) {
          encb[c] = __shfl(ze[c], j, 64) * invb;
          se = fma(encb[c], encb[c], se);
        }
        const double* __restrict__ cbr = cbn64 + (size_t)i*KCB*CD;
        const double* __restrict__ s64 = scbk64 + i*KCB;
        double bd = 1e300;
        int bk = 0;
#pragma unroll 2
        for (int it = 0; it < 16; it++) {
          int k = it*64 + lane;
          const double* row = cbr + (size_t)k*CD;
          double dot = 0.0;
#pragma unroll
          for (int c = 0; c < CD; c++) dot = fma(encb[c], row[c], dot);
          double dist = fma(-2.0, dot, se) + s64[k];
          if (dist < bd) { bd = dist; bk = k; }       // ascending k -> first index
        }
#pragma unroll
        for (int m = 1; m <= 32; m <<= 1) {
          double od = __shfl_xor(bd, m, 64);
          int    ok = __shfl_xor(bk, m, 64);
          bool take = (od < bd) || (od == bd && ok < bk);
          bd = take ? od : bd;
          bk = take ? ok : bk;
        }
        if (lane == j) bidxF = bk;
      }
    }

    // ---- gather raw codebook row
    const float4* __restrict__ qrow = (const float4*)(cb + (size_t)(i*KCB + bidxF)*CD);
    float4 q0 = qrow[0], q1 = qrow[1];
    double zq[CD] = {(double)q0.x, (double)q0.y, (double)q0.z, (double)q0.w,
                     (double)q1.x, (double)q1.y, (double)q1.z, (double)q1.w};

    // ---- losses
#pragma unroll
    for (int c = 0; c < CD; c++) {
      double dlt = ze[c] - zq[c];
      lacc = fma(dlt, dlt, lacc);
    }

    // ---- out_proj (f64) + residual update
#pragma unroll
    for (int d = 0; d < DD; d++) {
      double acc = bout64[i*DD + d];
#pragma unroll
      for (int c = 0; c < CD; c++)
        acc = fma(Wout64[(i*DD + d)*CD + c], zq[c], acc);
      r[d] -= acc;
    }

    // ---- codes
    out[CODES_OFF + (b*NCB + i)*TT + t] = (float)bidxF;
  }

  // ---- z_q = x - residual_final
#pragma unroll
  for (int d = 0; d < DD; d++)
    out[(b*DD + d)*TT + t] = (float)((double)x[(b*DD + d)*TT + t] - r[d]);

  // ---- deterministic loss reduction
#pragma unroll
  for (int off = 32; off > 0; off >>= 1)
    lacc += __shfl_down(lacc, off, 64);
  if ((threadIdx.x & 63) == 0) wsum[wv] = lacc;
  __syncthreads();
  if (threadIdx.x == 0)
    loss_part[blockIdx.x] = wsum[0] + wsum[1] + wsum[2] + wsum[3];
}

__global__ void loss_final(const double* __restrict__ loss_part,
                           float* __restrict__ out) {
  __shared__ double sh[256];
  double s = loss_part[threadIdx.x] + loss_part[threadIdx.x + 256];
  sh[threadIdx.x] = s;
  __syncthreads();
  for (int off = 128; off > 0; off >>= 1) {
    if (threadIdx.x < off) sh[threadIdx.x] += sh[threadIdx.x + off];
    __syncthreads();
  }
  if (threadIdx.x == 0) {
    double v = sh[0] / ((double)NCB * (double)BB * (double)CD * (double)TT);
    out[LOSS_OFF]     = (float)v;   // commit
    out[LOSS_OFF + 1] = (float)v;   // cb_loss (equal in forward value)
  }
}

extern "C" void kernel_launch(void* const* d_in, const int* in_sizes, int n_in,
                              void* d_out, int out_size, void* d_ws, size_t ws_size,
                              hipStream_t stream) {
  const float* x     = (const float*)d_in[0];
  const float* W_in  = (const float*)d_in[1];
  const float* b_in  = (const float*)d_in[2];
  const float* cb    = (const float*)d_in[3];
  const float* W_out = (const float*)d_in[4];
  const float* b_out = (const float*)d_in[5];
  float* out = (float*)d_out;

  char* ws = (char*)d_ws;
  unsigned* cbsplit = (unsigned*)(ws + OFF_CBSPLIT);
  double* cbn64  = (double*)(ws + OFF_CBN64);
  double* scbk64 = (double*)(ws + OFF_SCBK64);
  double* Win64  = (double*)(ws + OFF_WIN64);
  double* Wout64 = (double*)(ws + OFF_WOUT64);
  double* bin64  = (double*)(ws + OFF_BIN64);
  double* bout64 = (double*)(ws + OFF_BOUT64);
  double* loss_part = (double*)(ws + OFF_LOSSPART);

  prep_cb<<<(NCB*KCB + 255)/256, 256, 0, stream>>>(cb, cbsplit, cbn64, scbk64);
  prep_w<<<(NCB*CD*DD + 255)/256, 256, 0, stream>>>(W_in, b_in, W_out, b_out,
                                                    Win64, bin64, Wout64, bout64);
  rvq_kernel<<<(BB*TT)/256, 256, 0, stream>>>(x, cb, Win64, bin64, Wout64, bout64,
                                              cbsplit, cbn64, scbk64, out, loss_part);
  loss_final<<<1, 256, 0, stream>>>(loss_part, out);
}